// Round 7
// baseline (116.205 us; speedup 1.0000x reference)
//
#include <hip/hip_runtime.h>
#include <cstdint>
#include <cstddef>

#define DI __device__ __forceinline__

typedef __attribute__((ext_vector_type(8))) short short8;
typedef __attribute__((ext_vector_type(4))) float f32x4;

DI float bf2f(unsigned short u) {
  union { unsigned int i; float f; } c; c.i = ((unsigned int)u) << 16; return c.f;
}
DI unsigned short f2bf(float f) {
  union { float fl; unsigned int i; } c; c.fl = f;
  return (unsigned short)((c.i + 0x7FFFu + ((c.i >> 16) & 1u)) >> 16);
}
// HW packed f32->bf16 (RTNE), 1 VALU op for 2 converts.
DI unsigned int cvtpk(float lo, float hi) {
  unsigned int r;
  asm("v_cvt_pk_bf16_f32 %0, %1, %2" : "=v"(r) : "v"(lo), "v"(hi));
  return r;
}

// DPP lane-shuffled copy (quad_perm / row_ror): full-rate VALU, no LDS pipe.
template <int CTRL>
DI float dppf(float v) {
  return __int_as_float(__builtin_amdgcn_update_dpp(
      0, __float_as_int(v), CTRL, 0xF, 0xF, true));
}

// ---- workspace layout (bytes) ----
static const size_t OFF_MB   = 256;                       // u32[128] mask bitwords
static const size_t OFF_RBF  = 1024;                      // f32[136] rel_bias
static const size_t OFF_PBF  = 2048;                      // f32[512] proj_b
static const size_t OFF_AT   = 16384;                     // bf16 A_t[17][128][128]
static const size_t OFF_XQ   = OFF_AT + 557056;           // bf16 [2048][1024] (q|k)
static const size_t OFF_VT   = OFF_XQ + (size_t)4194304;  // bf16 [128bh][64d][128n]
static const size_t OFF_ATTO = OFF_VT + (size_t)2097152;  // bf16 [2048][512]
static const size_t OFF_PW   = OFF_ATTO + (size_t)2097152; // (reserved)
static const size_t OFF_XBF  = OFF_PW + (size_t)524288;   // bf16 x [2048][512]
static const size_t OFF_WBF  = OFF_XBF + (size_t)2097152; // bf16 [qw;kvw] [1536][512]

// ---- prep: 128 blocks. Detects dtype ON DEVICE (in_sizes are element counts —
//      cannot distinguish f32 from bf16 host-side). Repacks A_t + consts;
//      materializes bf16 XBF/WBF (convert if f32, copy if bf16) so the qkv
//      GEMM always runs the fast global_load_lds bf16 path. ----
__global__ __launch_bounds__(256) void k_prep(
    const void* __restrict__ x, const void* __restrict__ qw,
    const void* __restrict__ kvw, const void* __restrict__ as,
    const unsigned char* __restrict__ mr, const void* __restrict__ rb,
    const void* __restrict__ pb, unsigned char* __restrict__ ws) {
  __shared__ float sL[1088];
  __shared__ int s_c0, s_3f, s_b1, s_odd;
  const int t = threadIdx.x;
  const int blk = blockIdx.x;

  // fmode self-detect (proven heuristic): bf16 normals have exponent in
  // [64,150] for ~all elements; low-16 of f32 is ~uniform (~43/128 expected).
  if (t == 0) { s_c0 = 0; s_3f = 0; s_b1 = 0; s_odd = 0; }
  __syncthreads();
  if (t < 128) {
    unsigned short u = ((const unsigned short*)x)[2 * t];
    int e = (u >> 7) & 0xFF;
    if (e >= 64 && e <= 150) atomicAdd(&s_c0, 1);
  }
  __syncthreads();
  const int fmode = (s_c0 >= 96) ? 0 : 1;   // 1 = f32 inputs

  // ---- A_t repack via coalesced LDS transpose (128 mn-rows per block) ----
  unsigned short* At = (unsigned short*)(ws + OFF_AT);
  for (int gi = 0; gi < 2; gi++) {
    int mn0 = blk * 128 + gi * 64;
    for (int j = t; j < 1088; j += 256)
      sL[j] = fmode ? ((const float*)as)[(size_t)mn0 * 17 + j]
                    : bf2f(((const unsigned short*)as)[(size_t)mn0 * 17 + j]);
    __syncthreads();
    for (int w = t; w < 1088; w += 256) {
      int r = w >> 6, jj = w & 63;
      At[(size_t)r * 16384 + mn0 + jj] = f2bf(sL[jj * 17 + r]);
    }
    __syncthreads();
  }

  // ---- x -> XBF, [qw;kvw] -> WBF (bf16 mirror of GEMM inputs) ----
  unsigned short* XBF = (unsigned short*)(ws + OFF_XBF);
  unsigned short* WBF = (unsigned short*)(ws + OFF_WBF);
  if (fmode) {
    const float4* xf = (const float4*)x;
    for (int j = t; j < 2048; j += 256) {            // 262144 float4 total
      size_t idx = (size_t)blk * 2048 + j;
      float4 v = xf[idx];
      uint2 o; o.x = cvtpk(v.x, v.y); o.y = cvtpk(v.z, v.w);
      *(uint2*)&XBF[idx * 4] = o;
    }
    for (int j = t; j < 1536; j += 256) {            // 196608 float4 total
      size_t idx = (size_t)blk * 1536 + j;
      float4 v = (idx < 65536) ? ((const float4*)qw)[idx]
                               : ((const float4*)kvw)[idx - 65536];
      uint2 o; o.x = cvtpk(v.x, v.y); o.y = cvtpk(v.z, v.w);
      *(uint2*)&WBF[idx * 4] = o;
    }
  } else {
    const uint4* xs = (const uint4*)x;               // 131072 uint4 total
    for (int j = t; j < 1024; j += 256) {
      size_t idx = (size_t)blk * 1024 + j;
      ((uint4*)XBF)[idx] = xs[idx];
    }
    for (int j = t; j < 768; j += 256) {             // 98304 uint4 total
      size_t idx = (size_t)blk * 768 + j;
      ((uint4*)WBF)[idx] = (idx < 32768) ? ((const uint4*)qw)[idx]
                                         : ((const uint4*)kvw)[idx - 32768];
    }
  }

  if (blk == 0) {
    // mask-dtype detect (unchanged heuristic)
    {
      int f3 = 0, b1 = 0, od = 0;
      for (int i = t; i < 2176; i += 256) {
        unsigned char bb = mr[i];
        if (bb == 0x3F) f3 = 1;
        if (bb) { if ((i & 3) == 1) b1 = 1; if (i & 3) od = 1; }
      }
      if (f3) atomicOr(&s_3f, 1);
      if (b1) atomicOr(&s_b1, 1);
      if (od) atomicOr(&s_odd, 1);
    }
    __syncthreads();
    const int mmode = s_3f ? (s_b1 ? 2 : 3) : (s_odd ? 0 : 1);
    if (t == 0) { ((int*)ws)[0] = fmode; ((int*)ws)[1] = mmode; }
    unsigned int* MB = (unsigned int*)(ws + OFF_MB);
    float* RBf = (float*)(ws + OFF_RBF);
    float* PBf = (float*)(ws + OFF_PBF);
    if (t < 128) {
      unsigned int bits = 0;
      for (int r = 0; r < 17; r++) {
        int j = t * 17 + r, v;
        if (mmode == 0)      v = mr[j] != 0;
        else if (mmode == 1) v = ((const int*)mr)[j] != 0;
        else if (mmode == 2) v = ((const unsigned short*)mr)[j] != 0;
        else                 v = ((const float*)mr)[j] != 0.0f;
        bits |= (unsigned int)v << r;
      }
      MB[t] = bits;
    }
    for (int j = t; j < 136; j += 256)
      RBf[j] = fmode ? ((const float*)rb)[j] : bf2f(((const unsigned short*)rb)[j]);
    for (int j = t; j < 512; j += 256)
      PBf[j] = fmode ? ((const float*)pb)[j] : bf2f(((const unsigned short*)pb)[j]);
  }
}

// ---- qkv GEMM: C[2048,1536] = x @ [qw;kvw]^T, 64x64 tile, 768 blocks.
//      Pure bf16 global_load_lds path (inputs pre-materialized by k_prep). ----
__global__ __launch_bounds__(256) void k_gemm(unsigned char* __restrict__ ws) {
  __shared__ unsigned short As[64 * 64];
  __shared__ unsigned short Bs[64 * 64];
  const unsigned short* xb = (const unsigned short*)(ws + OFF_XBF);
  const unsigned short* wb = (const unsigned short*)(ws + OFF_WBF);
  const int t = threadIdx.x;
  const int gb2 = blockIdx.x;
  const int bm = (gb2 & 31) * 64, bn = (gb2 >> 5) * 64;
  const int wv = t >> 6, l = t & 63, ln = l & 15, qd = l >> 4;
  f32x4 acc[4] = {};
  const int g_row8 = l >> 3;
  const int g_ck = (l & 7) ^ g_row8;
  for (int k0 = 0; k0 < 512; k0 += 64) {
#pragma unroll
    for (int jj = 0; jj < 2; jj++) {
      int j = 2 * wv + jj;
      const unsigned short* g = xb + (size_t)(bm + j * 8 + g_row8) * 512 + k0 + g_ck * 8;
      __builtin_amdgcn_global_load_lds(
          (const __attribute__((address_space(1))) unsigned int*)g,
          (__attribute__((address_space(3))) unsigned int*)(&As[j * 512 + l * 8]),
          16, 0, 0);
    }
#pragma unroll
    for (int jj = 0; jj < 2; jj++) {
      int j = 2 * wv + jj;
      int row = bn + j * 8 + g_row8;
      const unsigned short* g = wb + (size_t)row * 512 + k0 + g_ck * 8;
      __builtin_amdgcn_global_load_lds(
          (const __attribute__((address_space(1))) unsigned int*)g,
          (__attribute__((address_space(3))) unsigned int*)(&Bs[j * 512 + l * 8]),
          16, 0, 0);
    }
    __syncthreads();
#pragma unroll
    for (int kk = 0; kk < 64; kk += 32) {
      int c = (kk >> 3) + qd;
      short8 af = *(const short8*)&As[(wv * 16 + ln) * 64 + ((c ^ (ln & 7)) * 8)];
#pragma unroll
      for (int tj = 0; tj < 4; tj++) {
        short8 bf = *(const short8*)&Bs[(tj * 16 + ln) * 64 + ((c ^ (ln & 7)) * 8)];
        acc[tj] = __builtin_amdgcn_mfma_f32_16x16x32_bf16(af, bf, acc[tj], 0, 0, 0);
      }
    }
    __syncthreads();
  }
  unsigned short* XQ = (unsigned short*)(ws + OFF_XQ);
  unsigned short* VT = (unsigned short*)(ws + OFF_VT);
#pragma unroll
  for (int tj = 0; tj < 4; tj++) {
    int col = bn + tj * 16 + ln;
    unsigned int p01 = cvtpk(acc[tj][0], acc[tj][1]);
    unsigned int p23 = cvtpk(acc[tj][2], acc[tj][3]);
    if (col >= 1024) {                       // V -> transposed, packed 8B store
      int c1 = col - 1024;
      int row0 = bm + wv * 16 + qd * 4;
      int bh = (row0 >> 7) * 8 + (c1 >> 6);
      uint2 pk2; pk2.x = p01; pk2.y = p23;
      *(uint2*)&VT[((size_t)bh * 64 + (c1 & 63)) * 128 + (row0 & 127)] = pk2;
    } else {
      int row0 = bm + wv * 16 + qd * 4;
      XQ[(size_t)(row0 + 0) * 1024 + col] = (unsigned short)p01;
      XQ[(size_t)(row0 + 1) * 1024 + col] = (unsigned short)(p01 >> 16);
      XQ[(size_t)(row0 + 2) * 1024 + col] = (unsigned short)p23;
      XQ[(size_t)(row0 + 3) * 1024 + col] = (unsigned short)(p23 >> 16);
    }
  }
}

// ---- attention (round-4 VERBATIM, proven): 1024 blocks -> bf16 ATTO ----
#define SST 132

__global__ __launch_bounds__(512) void k_attn_bf16(
    const unsigned short* __restrict__ XQ, const unsigned short* __restrict__ VT,
    const unsigned short* __restrict__ AT, const unsigned int* __restrict__ MB,
    const float* __restrict__ RBf, unsigned short* __restrict__ ATTO) {
  __shared__ __align__(16) float Sf[16 * SST];
  unsigned short* Wb = (unsigned short*)Sf;

  const int i0 = blockIdx.x;
  const int xcd = i0 & 7, slot = i0 >> 3;
  const int mq = xcd;
  const int bhid = slot;
  const int h = bhid & 7, b = bhid >> 3;
  const int bh = b * 8 + h;
  const int t = threadIdx.x;
  const int wv = t >> 6, l = t & 63, ln = l & 15, qd = l >> 4;
  const int ml = t >> 5, q32 = t & 31, n0 = q32 * 4;
  const int m = mq * 16 + ml;
  const unsigned short* abase = AT + (size_t)m * 128 + n0;
  uint2 ca = *(const uint2*)abase;
  uint2 cb = *(const uint2*)(abase + 16384);
  const unsigned int mb = MB[m];

  {
    const unsigned short* xqb = XQ + (size_t)(b * 128) * 1024 + h * 64;
    const unsigned short* qrow = xqb + (size_t)(mq * 16 + ln) * 1024;
    const unsigned short* krow = xqb + 512 + (size_t)(wv * 16 + ln) * 1024;
    f32x4 accS = {};
#pragma unroll
    for (int kk = 0; kk < 64; kk += 32) {
      short8 af = *(const short8*)(qrow + kk + qd * 8);
      short8 bf = *(const short8*)(krow + kk + qd * 8);
      accS = __builtin_amdgcn_mfma_f32_16x16x32_bf16(af, bf, accS, 0, 0, 0);
    }
#pragma unroll
    for (int i = 0; i < 4; i++)
      Sf[(qd * 4 + i) * SST + wv * 16 + ln] = accS[i] * 0.125f;
  }
  __syncthreads();

  {
    const float* rbh = RBf + h * 17;
    float sreg[4];
    {
      float4 s4 = *(const float4*)&Sf[ml * SST + n0];
      sreg[0] = s4.x; sreg[1] = s4.y; sreg[2] = s4.z; sreg[3] = s4.w;
    }
    float wacc[4] = {};
    float sum = 0.0f;
#pragma unroll
    for (int r = 0; r < 17; r++) {
      uint2 nn;
      if (r + 2 < 17) nn = *(const uint2*)(abase + (r + 2) * 16384);
      float av[4];
      const unsigned short* a8 = (const unsigned short*)&ca;
#pragma unroll
      for (int j = 0; j < 4; j++) av[j] = bf2f(a8[j]);
      float s = sreg[0] * av[0] + sreg[1] * av[1] + sreg[2] * av[2] + sreg[3] * av[3];
      s += dppf<0xB1>(s);
      s += dppf<0x4E>(s);
      s += dppf<0x124>(s);
      s += dppf<0x128>(s);
      s += __int_as_float(__builtin_amdgcn_ds_swizzle(__float_as_int(s), 0x401F));
      float e = ((mb >> r) & 1) ? 0.0f : __expf(s + rbh[r]);
      sum += e;
#pragma unroll
      for (int j = 0; j < 4; j++) wacc[j] += e * av[j];
      ca = cb; cb = nn;
    }
    const float inv = 1.0f / sum;
    uint2 o;
    o.x = cvtpk(wacc[0] * inv, wacc[1] * inv);
    o.y = cvtpk(wacc[2] * inv, wacc[3] * inv);
    *(uint2*)&Wb[ml * 264 + n0] = o;
  }
  __syncthreads();

  if (wv < 4) {
    f32x4 accO = {};
    const int d = wv * 16 + ln;
    const unsigned short* vrow = VT + ((size_t)bh * 64 + d) * 128;
#pragma unroll
    for (int kk = 0; kk < 128; kk += 32) {
      short8 af = *(const short8*)&Wb[ln * 264 + kk + qd * 8];
      short8 bf = *(const short8*)(vrow + kk + qd * 8);
      accO = __builtin_amdgcn_mfma_f32_16x16x32_bf16(af, bf, accO, 0, 0, 0);
    }
#pragma unroll
    for (int i = 0; i < 4; i++) {
      int row = b * 128 + mq * 16 + qd * 4 + i;
      ATTO[(size_t)row * 512 + h * 64 + d] = f2bf(accO[i]);
    }
  }
}

// ---- proj GEMM (round-4 VERBATIM, proven): 64x32 tiles, 512 blocks ----
__global__ __launch_bounds__(256) void k_proj(
    const unsigned short* __restrict__ A,   // ATTO bf16 [2048][512]
    const void* __restrict__ Bw,            // proj_w raw
    const float* __restrict__ biasf,
    const int* __restrict__ flags, void* __restrict__ C) {
  __shared__ unsigned short As[64 * 64];
  __shared__ unsigned short Bs[32 * 64];
  const int fmode = flags[0];
  const int bm = blockIdx.x * 64, bn = blockIdx.y * 32;
  const int t = threadIdx.x, wv = t >> 6, l = t & 63, ln = l & 15, qd = l >> 4;
  f32x4 acc[2] = {};
  const int g_row8 = l >> 3;
  const int g_ck = (l & 7) ^ g_row8;
  for (int k0 = 0; k0 < 512; k0 += 64) {
#pragma unroll
    for (int jj = 0; jj < 2; jj++) {
      int j = 2 * wv + jj;
      const unsigned short* g = A + (size_t)(bm + j * 8 + g_row8) * 512 + k0 + g_ck * 8;
      __builtin_amdgcn_global_load_lds(
          (const __attribute__((address_space(1))) unsigned int*)g,
          (__attribute__((address_space(3))) unsigned int*)(&As[j * 512 + l * 8]),
          16, 0, 0);
    }
    if (!fmode) {
      int row = bn + wv * 8 + g_row8;
      const unsigned short* g = (const unsigned short*)Bw + (size_t)row * 512 + k0 + g_ck * 8;
      __builtin_amdgcn_global_load_lds(
          (const __attribute__((address_space(1))) unsigned int*)g,
          (__attribute__((address_space(3))) unsigned int*)(&Bs[wv * 512 + l * 8]),
          16, 0, 0);
    } else {
      int row = t >> 3, cb = t & 7;     // 32 rows x 8 chunks
      const float* g = (const float*)Bw + (size_t)(bn + row) * 512 + k0 + cb * 8;
      unsigned int tb[4];
#pragma unroll
      for (int u = 0; u < 4; u++) tb[u] = cvtpk(g[2 * u], g[2 * u + 1]);
      int pc = cb ^ (row & 7);
      *(uint4*)&Bs[row * 64 + pc * 8] = *(const uint4*)tb;
    }
    __syncthreads();
#pragma unroll
    for (int kk = 0; kk < 64; kk += 32) {
      int c = (kk >> 3) + qd;
      short8 af = *(const short8*)&As[(wv * 16 + ln) * 64 + ((c ^ (ln & 7)) * 8)];
#pragma unroll
      for (int tj = 0; tj < 2; tj++) {
        short8 bf = *(const short8*)&Bs[(tj * 16 + ln) * 64 + ((c ^ (ln & 7)) * 8)];
        acc[tj] = __builtin_amdgcn_mfma_f32_16x16x32_bf16(af, bf, acc[tj], 0, 0, 0);
      }
    }
    __syncthreads();
  }
#pragma unroll
  for (int tj = 0; tj < 2; tj++) {
    int col = bn + tj * 16 + ln;
    float bv = biasf[col];
#pragma unroll
    for (int i = 0; i < 4; i++) {
      int row = bm + wv * 16 + qd * 4 + i;
      float v = acc[tj][i] + bv;
      if (fmode) ((float*)C)[(size_t)row * 512 + col] = v;
      else       ((unsigned short*)C)[(size_t)row * 512 + col] = f2bf(v);
    }
  }
}

extern "C" void kernel_launch(void* const* d_in, const int* in_sizes, int n_in,
                              void* d_out, int out_size, void* d_ws, size_t ws_size,
                              hipStream_t stream) {
  unsigned char* ws = (unsigned char*)d_ws;
  // 0:x 1:assignment 2:mask 3:q_w 4:kv_w 5:rel_bias 6:proj_w 7:proj_b
  // in_sizes are ELEMENT counts — dtype is detected on device by k_prep;
  // downstream kernels branch on the ws flag only.
  k_prep<<<128, 256, 0, stream>>>(d_in[0], d_in[3], d_in[4], d_in[1],
                                  (const unsigned char*)d_in[2],
                                  d_in[5], d_in[7], ws);
  k_gemm<<<768, 256, 0, stream>>>(ws);
  k_attn_bf16<<<1024, 512, 0, stream>>>(
      (const unsigned short*)(ws + OFF_XQ),
      (const unsigned short*)(ws + OFF_VT),
      (const unsigned short*)(ws + OFF_AT),
      (const unsigned int*)(ws + OFF_MB),
      (const float*)(ws + OFF_RBF),
      (unsigned short*)(ws + OFF_ATTO));
  k_proj<<<dim3(32, 16), 256, 0, stream>>>(
      (const unsigned short*)(ws + OFF_ATTO), d_in[6],
      (const float*)(ws + OFF_PBF), (const int*)ws, d_out);
}